// Round 4
// baseline (389.281 us; speedup 1.0000x reference)
//
#include <hip/hip_runtime.h>
#include <hip/hip_bf16.h>

typedef __attribute__((ext_vector_type(8))) short short8;
typedef __attribute__((ext_vector_type(4))) float f32x4;

#define NEDGES 800000
#define BM 64
#define CAT 384
#define APAD 10   // row stride = 394 shorts = 197 dwords (odd) -> conflict-free frag reads

__device__ __forceinline__ unsigned short f2bf(float f) {
  union { float f; unsigned u; } v; v.f = f;
  unsigned r = v.u + 0x7fffu + ((v.u >> 16) & 1u);
  return (unsigned short)(r >> 16);
}

__device__ __forceinline__ float bf2f(unsigned short u) {
  union { unsigned u; float f; } v; v.u = ((unsigned)u) << 16;
  return v.f;
}

// ---------------- prep kernels ----------------

__global__ void prep_w(const float* __restrict__ W1, const float* __restrict__ gamma,
                       const float* __restrict__ W2,
                       unsigned short* __restrict__ Wgt, unsigned short* __restrict__ W2t) {
  int idx = blockIdx.x * 256 + threadIdx.x;
  if (idx < 128 * 384) {
    int n = idx / 384, k = idx % 384;
    Wgt[idx] = f2bf(gamma[k] * W1[k * 128 + n]);
  }
  if (idx < 128 * 128) {
    int n = idx / 128, k = idx % 128;
    W2t[idx] = f2bf(W2[k * 128 + n]);
  }
}

__global__ void prep_gc(const float* __restrict__ W1, const float* __restrict__ gamma,
                        const float* __restrict__ beta, const float* __restrict__ b1,
                        float* __restrict__ G, float* __restrict__ C1) {
  int n = threadIdx.x;  // 128 threads
  float g = 0.f, b = 0.f;
  for (int k = 0; k < 384; ++k) {
    float w = W1[k * 128 + n];
    g = fmaf(gamma[k], w, g);
    b = fmaf(beta[k], w, b);
  }
  G[n] = g;
  C1[n] = b + b1[n];
}

// ---------------- fused main kernel ----------------
// Phase 1 is restructured for memory-level parallelism: ALL 24 float4 loads
// per thread are issued into live registers (ev/xiv/xjv arrays) BEFORE any
// use, so ~24 64B requests stay in flight per wave (was ~4 at VGPR=68).
__global__ __launch_bounds__(256, 3) void edge_fused(
    const float* __restrict__ node_feat,
    const int* __restrict__ esrc,
    const int* __restrict__ edst,
    const float* __restrict__ eptr,
    const unsigned short* __restrict__ Wgt,
    const unsigned short* __restrict__ W2t,
    const float* __restrict__ Gv,
    const float* __restrict__ C1v,
    const float* __restrict__ b2v,
    float* __restrict__ out) {
  __shared__ unsigned short Abuf[BM][CAT + APAD];
  __shared__ float muS[BM];
  __shared__ float rsS[BM];

  const int tid = threadIdx.x;
  const int blk = blockIdx.x;

  // ---------- Phase 1: gather + stats + bf16 staging (MLP-batched) ----------
  {
    const int r = tid >> 2;   // edge row (0..63)
    const int t = tid & 3;    // 4 threads per row
    const size_t gid = (size_t)blk * BM + r;
    const int si = esrc[gid];
    const int di = edst[gid];
    const float4* __restrict__ p2 = (const float4*)(eptr + gid * 128);
    const float4* __restrict__ p0 = (const float4*)(node_feat + (size_t)si * 128);
    const float4* __restrict__ p1 = (const float4*)(node_feat + (size_t)di * 128);

    float4 ev[8], xiv[8], xjv[8];
    // e loads first: independent of the index loads, fly during idx wait
#pragma unroll
    for (int i = 0; i < 8; ++i) ev[i] = p2[t + 4 * i];
#pragma unroll
    for (int i = 0; i < 8; ++i) xiv[i] = p0[t + 4 * i];
#pragma unroll
    for (int i = 0; i < 8; ++i) xjv[i] = p1[t + 4 * i];

    float sum = 0.f, sq = 0.f;
#pragma unroll
    for (int i = 0; i < 8; ++i) {
      float4 v = ev[i];
      sum += (v.x + v.y) + (v.z + v.w);
      sq = fmaf(v.x, v.x, sq); sq = fmaf(v.y, v.y, sq);
      sq = fmaf(v.z, v.z, sq); sq = fmaf(v.w, v.w, sq);
      ushort4 pk;
      pk.x = f2bf(v.x); pk.y = f2bf(v.y); pk.z = f2bf(v.z); pk.w = f2bf(v.w);
      *(ushort4*)&Abuf[r][256 + (t + 4 * i) * 4] = pk;
    }
#pragma unroll
    for (int i = 0; i < 8; ++i) {
      float4 v = xiv[i];
      sum += (v.x + v.y) + (v.z + v.w);
      sq = fmaf(v.x, v.x, sq); sq = fmaf(v.y, v.y, sq);
      sq = fmaf(v.z, v.z, sq); sq = fmaf(v.w, v.w, sq);
      ushort4 pk;
      pk.x = f2bf(v.x); pk.y = f2bf(v.y); pk.z = f2bf(v.z); pk.w = f2bf(v.w);
      *(ushort4*)&Abuf[r][0 + (t + 4 * i) * 4] = pk;
    }
#pragma unroll
    for (int i = 0; i < 8; ++i) {
      float4 v = xjv[i];
      sum += (v.x + v.y) + (v.z + v.w);
      sq = fmaf(v.x, v.x, sq); sq = fmaf(v.y, v.y, sq);
      sq = fmaf(v.z, v.z, sq); sq = fmaf(v.w, v.w, sq);
      ushort4 pk;
      pk.x = f2bf(v.x); pk.y = f2bf(v.y); pk.z = f2bf(v.z); pk.w = f2bf(v.w);
      *(ushort4*)&Abuf[r][128 + (t + 4 * i) * 4] = pk;
    }

    sum += __shfl_xor(sum, 1); sum += __shfl_xor(sum, 2);
    sq  += __shfl_xor(sq, 1);  sq  += __shfl_xor(sq, 2);
    const float mu = sum * (1.f / 384.f);
    const float var = fmaf(-mu, mu, sq * (1.f / 384.f));
    const float rstd = rsqrtf(var + 1e-5f);
    if (t == 0) { muS[r] = mu; rsS[r] = rstd; }
  }

  const int l = tid & 63;
  const int w = tid >> 6;        // wave 0..3 owns n-cols [32w, 32w+32)
  const int lr = l & 15;
  const int lkrow = l >> 4;
  const int lk = lkrow * 8;
  const int n0 = w * 32;

  // L2-resident per-n constants + first B-frag, issued pre-barrier
  float Gn[2], C1n[2];
  float4 b2q[2];
  short8 bfr[2];
#pragma unroll
  for (int nf = 0; nf < 2; ++nf) {
    const int n = n0 + nf * 16 + lr;
    Gn[nf] = Gv[n]; C1n[nf] = C1v[n];
    b2q[nf] = *(const float4*)&b2v[n0 + nf * 16 + lkrow * 4];
    bfr[nf] = *(const short8*)&Wgt[(size_t)n * CAT + lk];
  }

  __syncthreads();

  // ---------- GEMM1: [64 x 384] @ [384 x 128] ----------
  f32x4 acc[4][2];
#pragma unroll
  for (int mf = 0; mf < 4; ++mf)
#pragma unroll
    for (int nf = 0; nf < 2; ++nf)
      acc[mf][nf] = (f32x4){0.f, 0.f, 0.f, 0.f};

  short8 af[4];
#pragma unroll
  for (int mf = 0; mf < 4; ++mf)
    af[mf] = *(const short8*)&Abuf[mf * 16 + lr][lk];

#pragma unroll
  for (int kk = 0; kk < CAT; kk += 32) {
    short8 an[4], bn[2];
    if (kk + 32 < CAT) {
#pragma unroll
      for (int nf = 0; nf < 2; ++nf)
        bn[nf] = *(const short8*)&Wgt[(size_t)(n0 + nf * 16 + lr) * CAT + (kk + 32) + lk];
#pragma unroll
      for (int mf = 0; mf < 4; ++mf)
        an[mf] = *(const short8*)&Abuf[mf * 16 + lr][(kk + 32) + lk];
    }
#pragma unroll
    for (int mf = 0; mf < 4; ++mf)
#pragma unroll
      for (int nf = 0; nf < 2; ++nf)
        acc[mf][nf] = __builtin_amdgcn_mfma_f32_16x16x32_bf16(af[mf], bfr[nf], acc[mf][nf], 0, 0, 0);
    if (kk + 32 < CAT) {
#pragma unroll
      for (int mf = 0; mf < 4; ++mf) af[mf] = an[mf];
#pragma unroll
      for (int nf = 0; nf < 2; ++nf) bfr[nf] = bn[nf];
    }
  }

  __syncthreads();

  // epilogue 1: folded LN + bias + LeakyReLU -> h1 aliased on Abuf[:,0..127]
#pragma unroll
  for (int mf = 0; mf < 4; ++mf) {
#pragma unroll
    for (int nf = 0; nf < 2; ++nf) {
      const int n = n0 + nf * 16 + lr;
#pragma unroll
      for (int j = 0; j < 4; ++j) {
        const int m = mf * 16 + lkrow * 4 + j;
        float h = fmaf(rsS[m], acc[mf][nf][j] - muS[m] * Gn[nf], C1n[nf]);
        h = (h >= 0.f) ? h : 0.01f * h;
        Abuf[m][n] = f2bf(h);
      }
    }
  }
  __syncthreads();

  // ---------- GEMM2 (swapped): acc2 = (h1 @ W2)^T fragments ----------
  f32x4 acc2[4][2];
#pragma unroll
  for (int mf = 0; mf < 4; ++mf)
#pragma unroll
    for (int nf = 0; nf < 2; ++nf)
      acc2[mf][nf] = (f32x4){0.f, 0.f, 0.f, 0.f};

#pragma unroll
  for (int kk = 0; kk < 128; kk += 32) {
    short8 hb[4], wf[2];
#pragma unroll
    for (int mf = 0; mf < 4; ++mf)
      hb[mf] = *(const short8*)&Abuf[mf * 16 + lr][kk + lk];
#pragma unroll
    for (int nf = 0; nf < 2; ++nf)
      wf[nf] = *(const short8*)&W2t[(size_t)(n0 + nf * 16 + lr) * 128 + kk + lk];
#pragma unroll
    for (int mf = 0; mf < 4; ++mf)
#pragma unroll
      for (int nf = 0; nf < 2; ++nf)
        acc2[mf][nf] = __builtin_amdgcn_mfma_f32_16x16x32_bf16(wf[nf], hb[mf], acc2[mf][nf], 0, 0, 0);
  }

  // epilogue 2: out = e(bf16, LDS) + h2 + b2, one float4 store per fragment
  const size_t base = (size_t)blk * BM * 128;
#pragma unroll
  for (int mf = 0; mf < 4; ++mf) {
    const int m = mf * 16 + lr;
#pragma unroll
    for (int nf = 0; nf < 2; ++nf) {
      const int nb = n0 + nf * 16 + lkrow * 4;
      ushort4 ev = *(const ushort4*)&Abuf[m][256 + nb];
      float4 o;
      o.x = bf2f(ev.x) + acc2[mf][nf][0] + b2q[nf].x;
      o.y = bf2f(ev.y) + acc2[mf][nf][1] + b2q[nf].y;
      o.z = bf2f(ev.z) + acc2[mf][nf][2] + b2q[nf].z;
      o.w = bf2f(ev.w) + acc2[mf][nf][3] + b2q[nf].w;
      *(float4*)&out[base + (size_t)m * 128 + nb] = o;
    }
  }
}

extern "C" void kernel_launch(void* const* d_in, const int* in_sizes, int n_in,
                              void* d_out, int out_size, void* d_ws, size_t ws_size,
                              hipStream_t stream) {
  const float* node_feat = (const float*)d_in[0];
  const int* esrc        = (const int*)d_in[1];
  const int* edst        = (const int*)d_in[2];
  const float* e         = (const float*)d_in[3];
  const float* gamma     = (const float*)d_in[4];
  const float* beta      = (const float*)d_in[5];
  const float* W1        = (const float*)d_in[6];
  const float* b1        = (const float*)d_in[7];
  const float* W2        = (const float*)d_in[8];
  const float* b2        = (const float*)d_in[9];
  float* out = (float*)d_out;

  unsigned short* Wgt = (unsigned short*)d_ws;        // 128*384 bf16
  unsigned short* W2t = Wgt + 128 * 384;              // 128*128 bf16
  float* G  = (float*)(W2t + 128 * 128);
  float* C1 = G + 128;

  prep_w<<<192, 256, 0, stream>>>(W1, gamma, W2, Wgt, W2t);
  prep_gc<<<1, 128, 0, stream>>>(W1, gamma, beta, b1, G, C1);

  edge_fused<<<NEDGES / BM, 256, 0, stream>>>(node_feat, esrc, edst, e,
                                              Wgt, W2t, G, C1, b2, out);
}

// Round 5
// 270.713 us; speedup vs baseline: 1.4380x; 1.4380x over previous
//
#include <hip/hip_runtime.h>
#include <hip/hip_bf16.h>

typedef __attribute__((ext_vector_type(8))) short short8;
typedef __attribute__((ext_vector_type(4))) float f32x4;

#define NEDGES 800000
#define BM 32
#define NTILES (NEDGES / BM)   // 25000
#define CAT 384
#define APAD 8
#define STRIDE (CAT + APAD)
#define GRIDSZ 512             // 2 persistent blocks per CU

__device__ __forceinline__ unsigned short f2bf(float f) {
  union { float f; unsigned u; } v; v.f = f;
  unsigned r = v.u + 0x7fffu + ((v.u >> 16) & 1u);
  return (unsigned short)(r >> 16);
}

__device__ __forceinline__ float bf2f(unsigned short u) {
  union { unsigned u; float f; } v; v.u = ((unsigned)u) << 16;
  return v.f;
}

// ---------------- prep kernels ----------------

__global__ void prep_w(const float* __restrict__ W1, const float* __restrict__ gamma,
                       const float* __restrict__ W2,
                       unsigned short* __restrict__ Wgt, unsigned short* __restrict__ W2t) {
  int idx = blockIdx.x * 256 + threadIdx.x;
  if (idx < 128 * 384) {
    int n = idx / 384, k = idx % 384;
    Wgt[idx] = f2bf(gamma[k] * W1[k * 128 + n]);
  }
  if (idx < 128 * 128) {
    int n = idx / 128, k = idx % 128;
    W2t[idx] = f2bf(W2[k * 128 + n]);
  }
}

__global__ void prep_gc(const float* __restrict__ W1, const float* __restrict__ gamma,
                        const float* __restrict__ beta, const float* __restrict__ b1,
                        float* __restrict__ G, float* __restrict__ C1) {
  int n = threadIdx.x;  // 128 threads
  float g = 0.f, b = 0.f;
  for (int k = 0; k < 384; ++k) {
    float w = W1[k * 128 + n];
    g = fmaf(gamma[k], w, g);
    b = fmaf(beta[k], w, b);
  }
  G[n] = g;
  C1[n] = b + b1[n];
}

// ---------------- fused persistent pipelined kernel ----------------
// 512 persistent blocks, each grid-strides tiles of 32 edges with a
// double-buffered LDS A-tile. Weights live in registers (B1 96 + B2 32
// VGPR) so the GEMM phases issue ZERO global loads -> the gather loads
// for tile t+1 (issued at the end of iter t) stay in flight across the
// whole GEMM pipeline of tile t (vmcnt is in-order; any global load
// inside the GEMMs would force draining the gathers).
__global__ __launch_bounds__(256, 2) void edge_fused(
    const float* __restrict__ node_feat,
    const int* __restrict__ esrc,
    const int* __restrict__ edst,
    const float* __restrict__ eptr,
    const unsigned short* __restrict__ Wgt,
    const unsigned short* __restrict__ W2t,
    const float* __restrict__ Gv,
    const float* __restrict__ C1v,
    const float* __restrict__ b2v,
    float* __restrict__ out) {
  __shared__ unsigned short Abuf[2][BM][STRIDE];   // 2 x 32 x 392 x 2B = 50176 B
  __shared__ float muS[2][BM];
  __shared__ float rsS[2][BM];

  const int tid = threadIdx.x;
  const int r  = tid >> 3;      // gather row 0..31
  const int tt = tid & 7;       // 8 threads per row
  const int l = tid & 63;
  const int w = tid >> 6;       // wave 0..3 owns n-cols [32w,32w+32)
  const int lr = l & 15;
  const int lkrow = l >> 4;
  const int lk = lkrow * 8;
  const int n0 = w * 32;

  // ---- loop-invariant weights & constants -> registers ----
  short8 B1[2][12];   // GEMM1 B-frags: [nf][kstep]
  short8 B2[2][4];    // GEMM2 A-frags (swapped GEMM): [nf][kstep]
  float Gn[2], C1n[2];
  float4 b2q[2];
#pragma unroll
  for (int nf = 0; nf < 2; ++nf) {
    const int n = n0 + nf * 16 + lr;
    Gn[nf] = Gv[n]; C1n[nf] = C1v[n];
    b2q[nf] = *(const float4*)&b2v[n0 + nf * 16 + lkrow * 4];
#pragma unroll
    for (int ks = 0; ks < 12; ++ks)
      B1[nf][ks] = *(const short8*)&Wgt[(size_t)n * CAT + ks * 32 + lk];
#pragma unroll
    for (int ks = 0; ks < 4; ++ks)
      B2[nf][ks] = *(const short8*)&W2t[(size_t)n * 128 + ks * 32 + lk];
  }

  float4 ev[4], xi[4], xj[4];
  int siP, diP;   // prefetched indices for the NEXT tile to be gathered

  // ---- staging helper (regs -> bf16 LDS + LN stats), as a lambda ----
  auto stage = [&](int q) {
    float sum = 0.f, sq = 0.f;
#pragma unroll
    for (int i = 0; i < 4; ++i) {
      float4 v = ev[i];
      sum += (v.x + v.y) + (v.z + v.w);
      sq = fmaf(v.x, v.x, sq); sq = fmaf(v.y, v.y, sq);
      sq = fmaf(v.z, v.z, sq); sq = fmaf(v.w, v.w, sq);
      ushort4 pk; pk.x = f2bf(v.x); pk.y = f2bf(v.y); pk.z = f2bf(v.z); pk.w = f2bf(v.w);
      *(ushort4*)&Abuf[q][r][256 + (tt + 8 * i) * 4] = pk;
    }
#pragma unroll
    for (int i = 0; i < 4; ++i) {
      float4 v = xi[i];
      sum += (v.x + v.y) + (v.z + v.w);
      sq = fmaf(v.x, v.x, sq); sq = fmaf(v.y, v.y, sq);
      sq = fmaf(v.z, v.z, sq); sq = fmaf(v.w, v.w, sq);
      ushort4 pk; pk.x = f2bf(v.x); pk.y = f2bf(v.y); pk.z = f2bf(v.z); pk.w = f2bf(v.w);
      *(ushort4*)&Abuf[q][r][0 + (tt + 8 * i) * 4] = pk;
    }
#pragma unroll
    for (int i = 0; i < 4; ++i) {
      float4 v = xj[i];
      sum += (v.x + v.y) + (v.z + v.w);
      sq = fmaf(v.x, v.x, sq); sq = fmaf(v.y, v.y, sq);
      sq = fmaf(v.z, v.z, sq); sq = fmaf(v.w, v.w, sq);
      ushort4 pk; pk.x = f2bf(v.x); pk.y = f2bf(v.y); pk.z = f2bf(v.z); pk.w = f2bf(v.w);
      *(ushort4*)&Abuf[q][r][128 + (tt + 8 * i) * 4] = pk;
    }
    sum += __shfl_xor(sum, 1); sum += __shfl_xor(sum, 2); sum += __shfl_xor(sum, 4);
    sq  += __shfl_xor(sq, 1);  sq  += __shfl_xor(sq, 2);  sq  += __shfl_xor(sq, 4);
    const float mu = sum * (1.f / 384.f);
    const float var = fmaf(-mu, mu, sq * (1.f / 384.f));
    const float rstd = rsqrtf(var + 1e-5f);
    if (tt == 0) { muS[q][r] = mu; rsS[q][r] = rstd; }
  };

  auto gather = [&](int tl) {  // issue 12 float4 loads for tile tl (uses siP/diP)
    const size_t g = (size_t)tl * BM + r;
    const float4* __restrict__ pe = (const float4*)(eptr + g * 128);
    const float4* __restrict__ pi = (const float4*)(node_feat + (size_t)siP * 128);
    const float4* __restrict__ pj = (const float4*)(node_feat + (size_t)diP * 128);
#pragma unroll
    for (int i = 0; i < 4; ++i) ev[i] = pe[tt + 8 * i];
#pragma unroll
    for (int i = 0; i < 4; ++i) xi[i] = pi[tt + 8 * i];
#pragma unroll
    for (int i = 0; i < 4; ++i) xj[i] = pj[tt + 8 * i];
  };

  // ---- prologue: tile0 gathered+staged; tile1 gather in flight ----
  int tile = blockIdx.x;
  {
    const size_t g0 = (size_t)tile * BM + r;
    siP = esrc[g0]; diP = edst[g0];
    gather(tile);
  }
  int tnext = tile + GRIDSZ;
  if (tnext < NTILES) {
    const size_t g1 = (size_t)tnext * BM + r;
    siP = esrc[g1]; diP = edst[g1];
  }
  stage(0);
  if (tnext < NTILES) {
    gather(tnext);
    const int t3 = tnext + GRIDSZ;
    if (t3 < NTILES) {
      const size_t g3 = (size_t)t3 * BM + r;
      siP = esrc[g3]; diP = edst[g3];
    }
  }
  __syncthreads();

  int p = 0;
  for (;;) {
    // ---------- GEMM1 (zero global loads) ----------
    f32x4 acc[2][2];
#pragma unroll
    for (int mf = 0; mf < 2; ++mf)
#pragma unroll
      for (int nf = 0; nf < 2; ++nf)
        acc[mf][nf] = (f32x4){0.f, 0.f, 0.f, 0.f};
#pragma unroll
    for (int ks = 0; ks < 12; ++ks) {
      short8 af0 = *(const short8*)&Abuf[p][lr][ks * 32 + lk];
      short8 af1 = *(const short8*)&Abuf[p][16 + lr][ks * 32 + lk];
      acc[0][0] = __builtin_amdgcn_mfma_f32_16x16x32_bf16(af0, B1[0][ks], acc[0][0], 0, 0, 0);
      acc[0][1] = __builtin_amdgcn_mfma_f32_16x16x32_bf16(af0, B1[1][ks], acc[0][1], 0, 0, 0);
      acc[1][0] = __builtin_amdgcn_mfma_f32_16x16x32_bf16(af1, B1[0][ks], acc[1][0], 0, 0, 0);
      acc[1][1] = __builtin_amdgcn_mfma_f32_16x16x32_bf16(af1, B1[1][ks], acc[1][1], 0, 0, 0);
    }
    __syncthreads();   // all waves done reading x-sections of buf[p]

    // epi1: folded LN + bias + LeakyReLU -> h1 aliased on buf[p] cols 0..127
#pragma unroll
    for (int mf = 0; mf < 2; ++mf) {
#pragma unroll
      for (int nf = 0; nf < 2; ++nf) {
        const int n = n0 + nf * 16 + lr;
#pragma unroll
        for (int j = 0; j < 4; ++j) {
          const int m = mf * 16 + lkrow * 4 + j;
          float h = fmaf(rsS[p][m], acc[mf][nf][j] - muS[p][m] * Gn[nf], C1n[nf]);
          h = (h >= 0.f) ? h : 0.01f * h;
          Abuf[p][m][n] = f2bf(h);
        }
      }
    }
    __syncthreads();

    // ---------- GEMM2 (swapped, zero global loads) ----------
    f32x4 acc2[2][2];
#pragma unroll
    for (int mf = 0; mf < 2; ++mf)
#pragma unroll
      for (int nf = 0; nf < 2; ++nf)
        acc2[mf][nf] = (f32x4){0.f, 0.f, 0.f, 0.f};
#pragma unroll
    for (int ks = 0; ks < 4; ++ks) {
      short8 h0 = *(const short8*)&Abuf[p][lr][ks * 32 + lk];
      short8 h1 = *(const short8*)&Abuf[p][16 + lr][ks * 32 + lk];
      acc2[0][0] = __builtin_amdgcn_mfma_f32_16x16x32_bf16(B2[0][ks], h0, acc2[0][0], 0, 0, 0);
      acc2[0][1] = __builtin_amdgcn_mfma_f32_16x16x32_bf16(B2[1][ks], h0, acc2[0][1], 0, 0, 0);
      acc2[1][0] = __builtin_amdgcn_mfma_f32_16x16x32_bf16(B2[0][ks], h1, acc2[1][0], 0, 0, 0);
      acc2[1][1] = __builtin_amdgcn_mfma_f32_16x16x32_bf16(B2[1][ks], h1, acc2[1][1], 0, 0, 0);
    }

    // epi2: out = e(bf16, LDS) + h2 + b2  (float4 stores)
    const size_t base = (size_t)tile * BM * 128;
#pragma unroll
    for (int mf = 0; mf < 2; ++mf) {
      const int m = mf * 16 + lr;
#pragma unroll
      for (int nf = 0; nf < 2; ++nf) {
        const int nb = n0 + nf * 16 + lkrow * 4;
        ushort4 e4 = *(const ushort4*)&Abuf[p][m][256 + nb];
        float4 o;
        o.x = bf2f(e4.x) + acc2[mf][nf][0] + b2q[nf].x;
        o.y = bf2f(e4.y) + acc2[mf][nf][1] + b2q[nf].y;
        o.z = bf2f(e4.z) + acc2[mf][nf][2] + b2q[nf].z;
        o.w = bf2f(e4.w) + acc2[mf][nf][3] + b2q[nf].w;
        *(float4*)&out[base + (size_t)m * 128 + nb] = o;
      }
    }

    if (tnext >= NTILES) break;

    // stage tnext's regs -> buf[p^1] (gathers were issued a full iter ago)
    stage(p ^ 1);

    // issue gathers for t3 = tnext+GRIDSZ, prefetch idx for t4
    const int t3 = tnext + GRIDSZ;
    if (t3 < NTILES) {
      gather(t3);
      const int t4 = t3 + GRIDSZ;
      if (t4 < NTILES) {
        const size_t g4 = (size_t)t4 * BM + r;
        siP = esrc[g4]; diP = edst[g4];
      }
    }
    __syncthreads();
    p ^= 1;
    tile = tnext;
    tnext = t3;
  }
}

extern "C" void kernel_launch(void* const* d_in, const int* in_sizes, int n_in,
                              void* d_out, int out_size, void* d_ws, size_t ws_size,
                              hipStream_t stream) {
  const float* node_feat = (const float*)d_in[0];
  const int* esrc        = (const int*)d_in[1];
  const int* edst        = (const int*)d_in[2];
  const float* e         = (const float*)d_in[3];
  const float* gamma     = (const float*)d_in[4];
  const float* beta      = (const float*)d_in[5];
  const float* W1        = (const float*)d_in[6];
  const float* b1        = (const float*)d_in[7];
  const float* W2        = (const float*)d_in[8];
  const float* b2        = (const float*)d_in[9];
  float* out = (float*)d_out;

  unsigned short* Wgt = (unsigned short*)d_ws;        // 128*384 bf16
  unsigned short* W2t = Wgt + 128 * 384;              // 128*128 bf16
  float* G  = (float*)(W2t + 128 * 128);
  float* C1 = G + 128;

  prep_w<<<192, 256, 0, stream>>>(W1, gamma, W2, Wgt, W2t);
  prep_gc<<<1, 128, 0, stream>>>(W1, gamma, beta, b1, G, C1);

  edge_fused<<<GRIDSZ, 256, 0, stream>>>(node_feat, esrc, edst, e,
                                         Wgt, W2t, G, C1, b2, out);
}